// Round 11
// baseline (95.772 us; speedup 1.0000x reference)
//
#include <hip/hip_runtime.h>
#include <stdint.h>

#define B_ 4
#define N_ 4096
#define Q_ 4096
#define K_ 32
#define E_ 32
#define R_ 16
#define F_ 53   // 3 rel_pos + 1 radius + 32 emb + 16 rbf + 1 dist

static constexpr int WAVES   = 16;           // waves per block, 1 query each
static constexpr int THREADS = WAVES * 64;   // 1024
static constexpr int CAP     = 6;            // per-LANE candidate slots
static constexpr int CBUFW   = CAP * 64;     // u32 slots per wave
static constexpr int TILE    = K_ * F_;      // 1696 floats per query tile
static constexpr int NSLOT   = 4;            // stage slots time-shared by waves
static constexpr int POOLU   = WAVES * CBUFW + WAVES * 64;   // cbuf + compact
static constexpr int POOLB   = (POOLU * 4 > NSLOT * TILE * 4)
                             ? (POOLU * 4) : (NSLOT * TILE * 4);   // 28672 B

typedef float v2f __attribute__((ext_vector_type(2)));

// VOP3P packed fp32: 2 FP32 ops per instruction (per-half rounding == scalar rn)
__device__ __forceinline__ v2f pk_add(v2f a, v2f b) {
    v2f d; asm("v_pk_add_f32 %0, %1, %2" : "=v"(d) : "v"(a), "v"(b)); return d;
}
__device__ __forceinline__ v2f pk_mul(v2f a, v2f b) {
    v2f d; asm("v_pk_mul_f32 %0, %1, %2" : "=v"(d) : "v"(a), "v"(b)); return d;
}
__device__ __forceinline__ v2f pk_fma(v2f a, v2f b, v2f c) {
    v2f d; asm("v_pk_fma_f32 %0, %1, %2, %3" : "=v"(d) : "v"(a), "v"(b), "v"(c)); return d;
}
// packed squared distance (fma-space) for 2 atoms; coords pre-negated
__device__ __forceinline__ v2f pk_s2(v2f qx, v2f qy, v2f qz,
                                     v2f nx, v2f ny, v2f nz) {
    const v2f dx = pk_add(qx, nx);
    const v2f dy = pk_add(qy, ny);
    const v2f dz = pk_add(qz, nz);
    return pk_fma(dz, dz, pk_fma(dy, dy, pk_mul(dx, dx)));
}

__device__ __forceinline__ void bitonic_sort64_u32(unsigned int& v, int lane) {
    #pragma unroll
    for (int k = 2; k <= 64; k <<= 1) {
        #pragma unroll
        for (int j = k >> 1; j > 0; j >>= 1) {
            unsigned int o = __shfl_xor(v, j);
            const bool asc = ((lane & k) == 0);
            const bool lower = ((lane & j) == 0);
            unsigned int mn = v < o ? v : o;
            unsigned int mx = v < o ? o : v;
            v = (lower == asc) ? mn : mx;
        }
    }
}

__device__ __forceinline__ void bitonic_sort64_u64(unsigned long long& v, int lane) {
    #pragma unroll
    for (int k = 2; k <= 64; k <<= 1) {
        #pragma unroll
        for (int j = k >> 1; j > 0; j >>= 1) {
            unsigned long long o = __shfl_xor(v, j);
            const bool asc = ((lane & k) == 0);
            const bool lower = ((lane & j) == 0);
            unsigned long long mn = v < o ? v : o;
            unsigned long long mx = v < o ? o : v;
            v = (lower == asc) ? mn : mx;
        }
    }
}

__global__ __launch_bounds__(THREADS, 8)
void lfb_kernel(const float* __restrict__ coords,
                const int* __restrict__ atom_types,
                const float* __restrict__ radii,
                const float* __restrict__ qpts,
                const int* __restrict__ atom_mask,
                const int* __restrict__ query_mask,
                const float* __restrict__ embed,
                const float* __restrict__ centers,
                float* __restrict__ out)
{
    __shared__ __align__(16) float nsx[N_], nsy[N_], nsz[N_];  // NEGATED coords
    __shared__ __align__(16) unsigned char pool[POOLB];        // cand / stage

    const int tid  = threadIdx.x;
    const int lane = tid & 63;
    const int wv   = tid >> 6;
    const int bq0  = blockIdx.x * WAVES;
    const int b    = bq0 / Q_;

    // stage negated coords; masked atoms poisoned (-1e30 -> s == +inf bit-exact)
    for (int i = tid; i < N_; i += THREADS) {
        const float* c = coords + (size_t)(b * N_ + i) * 3;
        const bool mv = atom_mask[b * N_ + i] != 0;
        nsx[i] = mv ? -c[0] : -1e30f;
        nsy[i] = mv ? -c[1] : -1e30f;
        nsz[i] = mv ? -c[2] : -1e30f;
    }
    __syncthreads();

    const int bq = bq0 + wv;
    const float qx = qpts[(size_t)bq * 3 + 0];
    const float qy = qpts[(size_t)bq * 3 + 1];
    const float qz = qpts[(size_t)bq * 3 + 2];
    const v2f qx2 = {qx, qx}, qy2 = {qy, qy}, qz2 = {qz, qz};

    const float INFf = __uint_as_float(0x7F800000u);

    // ---- pass 1: full-scan per-lane minima of packed-fma squared dist ----
    float l0 = INFf, l1 = INFf, l2 = INFf, l3 = INFf;
    for (int i = 0; i < N_ / 256; ++i) {
        const int a0 = i * 256 + lane * 4;
        const float4 X = *(const float4*)&nsx[a0];
        const float4 Y = *(const float4*)&nsy[a0];
        const float4 Z = *(const float4*)&nsz[a0];
        const v2f Xl = {X.x, X.y}, Xh = {X.z, X.w};
        const v2f Yl = {Y.x, Y.y}, Yh = {Y.z, Y.w};
        const v2f Zl = {Z.x, Z.y}, Zh = {Z.z, Z.w};
        const v2f sl = pk_s2(qx2, qy2, qz2, Xl, Yl, Zl);
        const v2f sh = pk_s2(qx2, qy2, qz2, Xh, Yh, Zh);
        l0 = fminf(l0, sl.x); l1 = fminf(l1, sl.y);
        l2 = fminf(l2, sh.x); l3 = fminf(l3, sh.y);
    }
    unsigned int mnb = __float_as_uint(fminf(fminf(l0, l1), fminf(l2, l3)));
    bitonic_sort64_u32(mnb, lane);
    const unsigned int Ts = __shfl(mnb, 31);   // 32 witness atoms have s <= Ts
    // +64 bit-steps: fma-vs-exact slop. Guard BOTH inf Ts and slop-overflow
    // into inf/NaN space (would make the float threshold compare garbage).
    const bool degenerate = (Ts + 64u) >= 0x7F800000u;
    const float STf = __uint_as_float(Ts + 64u);

    // ---- pass 2: per-lane slot collection, ZERO wave coordination ----
    unsigned int* poolu = reinterpret_cast<unsigned int*>(pool);
    unsigned int* cbuf = poolu + wv * CBUFW;            // [CAP][64] u32
    unsigned int* comp = poolu + WAVES * CBUFW + wv * 64;
    int cl = 0;
    for (int i = 0; i < N_ / 256; ++i) {
        const int a0 = i * 256 + lane * 4;
        const float4 X = *(const float4*)&nsx[a0];
        const float4 Y = *(const float4*)&nsy[a0];
        const float4 Z = *(const float4*)&nsz[a0];
        const v2f Xl = {X.x, X.y}, Xh = {X.z, X.w};
        const v2f Yl = {Y.x, Y.y}, Yh = {Y.z, Y.w};
        const v2f Zl = {Z.x, Z.y}, Zh = {Z.z, Z.w};
        const v2f sl = pk_s2(qx2, qy2, qz2, Xl, Yl, Zl);
        const v2f sh = pk_s2(qx2, qy2, qz2, Xh, Yh, Zh);
        // unconditional write to slot min(cl,CAP-1); junk is overwritten by the
        // next candidate; increment only on hit. No ballot/popc/branch.
        {
            const int s0 = cl < CAP ? cl : CAP - 1;
            cbuf[s0 * 64 + lane] = (unsigned int)(a0 + 0);
            cl += (sl.x <= STf) ? 1 : 0;
        }
        {
            const int s1 = cl < CAP ? cl : CAP - 1;
            cbuf[s1 * 64 + lane] = (unsigned int)(a0 + 1);
            cl += (sl.y <= STf) ? 1 : 0;
        }
        {
            const int s2 = cl < CAP ? cl : CAP - 1;
            cbuf[s2 * 64 + lane] = (unsigned int)(a0 + 2);
            cl += (sh.x <= STf) ? 1 : 0;
        }
        {
            const int s3 = cl < CAP ? cl : CAP - 1;
            cbuf[s3 * 64 + lane] = (unsigned int)(a0 + 3);
            cl += (sh.y <= STf) ? 1 : 0;
        }
    }
    // cl == CAP is ALSO unsafe: once slots are full, later junk writes land on
    // slot CAP-1 and can overwrite the last valid candidate undetected (r10 bug).
    const bool ovf = __ballot(cl >= CAP) != 0ull;

    // exclusive prefix sum of per-lane counts -> compact offsets
    int x = cl;
    #pragma unroll
    for (int j = 1; j < 64; j <<= 1) {
        const int t = __shfl_up(x, j);
        if (lane >= j) x += t;
    }
    const int excl = x - cl;
    const int tcnt = __shfl(x, 63);

    // exact reference re-key (rn ops, fixed association, eps, CR sqrt)
    auto rekey = [&](int id) -> unsigned long long {
        const float dx = __fadd_rn(qx, nsx[id]);
        const float dy = __fadd_rn(qy, nsy[id]);
        const float dz = __fadd_rn(qz, nsz[id]);
        const float sv = __fadd_rn(
            __fadd_rn(__fmul_rn(dx, dx), __fmul_rn(dy, dy)),
            __fmul_rn(dz, dz));
        const float d = __fsqrt_rn(__fadd_rn(sv, 1e-12f));
        return ((unsigned long long)__float_as_uint(d) << 32) | (unsigned int)id;
    };

    unsigned long long key;
    if (!degenerate && !ovf && tcnt <= 64) {
        // compact (same-wave LDS, in-order) then one exact u64 sort
        for (int j = 0; j < cl; ++j) comp[excl + j] = cbuf[j * 64 + lane];
        unsigned long long v = ~0ull;
        if (lane < tcnt) v = rekey((int)comp[lane]);
        bitonic_sort64_u64(v, lane);
        key = v;
    } else {
        // fallback (degenerate masks / slot overflow / tcnt>64): exact streaming
        key = ~0ull;
        for (int base = 0; base < N_; base += 64) {
            const unsigned long long cand = rekey(base + lane);
            const unsigned long long T = __shfl(key, 31);
            unsigned long long m = __ballot(cand < T);
            while (m) {
                const int src = __ffsll(m) - 1;
                m &= m - 1;
                const unsigned long long nk = __shfl(cand, src);
                const unsigned long long up = __shfl_up(key, 1);
                if (lane < K_) {
                    const unsigned long long repl =
                        (lane == 0) ? nk : (up <= nk ? nk : up);
                    key = (key <= nk) ? key : repl;
                }
            }
        }
    }

    const size_t BQK = (size_t)B_ * Q_ * K_;
    float* out_feat = out;
    float* out_mask = out + BQK * (size_t)F_;
    float* out_idx  = out_mask + BQK;
    float* out_dist = out_idx + BQK;

    const bool qm = query_mask[bq] != 0;

    const float d_l  = __uint_as_float((unsigned int)(key >> 32));
    const int   id_l = (int)(key & 0xFFFFFFFFull) & (N_ - 1);
    const bool  am_l = ((unsigned int)(key >> 32)) < 0x7F800000u;  // d < inf
    const bool  nm_l = am_l && (d_l <= 5.0f) && qm;

    // scalar outputs before the stage-overlay barrier
    if (lane < K_) {
        const size_t o = (size_t)bq * K_ + lane;
        out_mask[o] = nm_l ? 1.0f : 0.0f;
        out_idx[o]  = am_l ? (float)id_l : -1.0f;
        out_dist[o] = nm_l ? d_l : 0.0f;
    }

    __syncthreads();   // all cand-buffer reads done before stage overlay

    // ---- feature build: NSLOT stage slots, 4 barrier rounds ----
    float* stagef = reinterpret_cast<float*>(pool);
    for (int r = 0; r < WAVES / NSLOT; ++r) {
        if ((wv >> 2) == r) {
            float* f0 = stagef + (size_t)(wv & (NSLOT - 1)) * TILE;
            if (lane < K_) {
                float* f = f0 + lane * F_;
                f[0] = nm_l ? __fadd_rn(qx, nsx[id_l]) : 0.0f;
                f[1] = nm_l ? __fadd_rn(qy, nsy[id_l]) : 0.0f;
                f[2] = nm_l ? __fadd_rn(qz, nsz[id_l]) : 0.0f;
                f[3] = nm_l ? radii[b * N_ + id_l] : 0.0f;

                const int t = atom_types[b * N_ + id_l];
                const float4* er4 = (const float4*)(embed + t * E_);
                #pragma unroll
                for (int e = 0; e < E_ / 4; ++e) {
                    const float4 v = er4[e];
                    f[4 + e * 4 + 0] = nm_l ? v.x : 0.0f;
                    f[4 + e * 4 + 1] = nm_l ? v.y : 0.0f;
                    f[4 + e * 4 + 2] = nm_l ? v.z : 0.0f;
                    f[4 + e * 4 + 3] = nm_l ? v.w : 0.0f;
                }

                const float NG = -(float)(256.0 / 25.0);   // -RBF_GAMMA
                #pragma unroll
                for (int rr = 0; rr < R_; ++rr) {
                    const float dd = __fsub_rn(d_l, centers[rr]);
                    const float a2 = __fmul_rn(dd, dd);
                    f[36 + rr] = nm_l ? expf(__fmul_rn(NG, a2)) : 0.0f;
                }
                f[52] = nm_l ? d_l : 0.0f;
            }
            // same-wave LDS in-order: copy sees this wave's writes w/o barrier
            const float4* s4 = (const float4*)f0;
            float4* d4 = (float4*)(out_feat + (size_t)bq * (size_t)TILE);
            for (int t4 = lane; t4 < TILE / 4; t4 += 64) d4[t4] = s4[t4];
        }
        __syncthreads();
    }
}

extern "C" void kernel_launch(void* const* d_in, const int* in_sizes, int n_in,
                              void* d_out, int out_size, void* d_ws, size_t ws_size,
                              hipStream_t stream) {
    const float* coords     = (const float*)d_in[0];
    const int*   atom_types = (const int*)d_in[1];
    const float* radii      = (const float*)d_in[2];
    const float* qpts       = (const float*)d_in[3];
    const int*   atom_mask  = (const int*)d_in[4];
    const int*   query_mask = (const int*)d_in[5];
    const float* embed      = (const float*)d_in[6];
    const float* centers    = (const float*)d_in[7];

    dim3 grid((B_ * Q_) / WAVES);
    dim3 block(THREADS);
    lfb_kernel<<<grid, block, 0, stream>>>(coords, atom_types, radii, qpts,
                                           atom_mask, query_mask, embed, centers,
                                           (float*)d_out);
}

// Round 12
// 66.650 us; speedup vs baseline: 1.4369x; 1.4369x over previous
//
#include <hip/hip_runtime.h>
#include <stdint.h>

#define B_ 4
#define N_ 4096
#define Q_ 4096
#define K_ 32
#define E_ 32
#define R_ 16
#define F_ 53   // 3 rel_pos + 1 radius + 32 emb + 16 rbf + 1 dist

static constexpr int WAVES   = 16;           // waves per block, 1 query each
static constexpr int THREADS = WAVES * 64;   // 1024
static constexpr int CAP     = 208;          // per-query candidate capacity (u32)
static constexpr int TILE    = K_ * F_;      // 1696 floats per query tile
static constexpr int NSLOT   = 4;            // stage slots time-shared by waves
static constexpr int POOLB   = (WAVES * CAP * 4 > NSLOT * TILE * 4)
                             ? (WAVES * CAP * 4) : (NSLOT * TILE * 4); // 27136 B

typedef float v2f __attribute__((ext_vector_type(2)));

// VOP3P packed fp32: 2 FP32 ops per instruction (per-half rounding == scalar rn)
__device__ __forceinline__ v2f pk_add(v2f a, v2f b) {
    v2f d; asm("v_pk_add_f32 %0, %1, %2" : "=v"(d) : "v"(a), "v"(b)); return d;
}
__device__ __forceinline__ v2f pk_mul(v2f a, v2f b) {
    v2f d; asm("v_pk_mul_f32 %0, %1, %2" : "=v"(d) : "v"(a), "v"(b)); return d;
}
__device__ __forceinline__ v2f pk_fma(v2f a, v2f b, v2f c) {
    v2f d; asm("v_pk_fma_f32 %0, %1, %2, %3" : "=v"(d) : "v"(a), "v"(b), "v"(c)); return d;
}
// packed squared distance (fma-space) for 2 atoms; coords pre-negated
__device__ __forceinline__ v2f pk_s2(v2f qx, v2f qy, v2f qz,
                                     v2f nx, v2f ny, v2f nz) {
    const v2f dx = pk_add(qx, nx);
    const v2f dy = pk_add(qy, ny);
    const v2f dz = pk_add(qz, nz);
    return pk_fma(dz, dz, pk_fma(dy, dy, pk_mul(dx, dx)));
}

__device__ __forceinline__ void bitonic_sort64_u32(unsigned int& v, int lane) {
    #pragma unroll
    for (int k = 2; k <= 64; k <<= 1) {
        #pragma unroll
        for (int j = k >> 1; j > 0; j >>= 1) {
            unsigned int o = __shfl_xor(v, j);
            const bool asc = ((lane & k) == 0);
            const bool lower = ((lane & j) == 0);
            unsigned int mn = v < o ? v : o;
            unsigned int mx = v < o ? o : v;
            v = (lower == asc) ? mn : mx;
        }
    }
}

__device__ __forceinline__ void bitonic_sort64_u64(unsigned long long& v, int lane) {
    #pragma unroll
    for (int k = 2; k <= 64; k <<= 1) {
        #pragma unroll
        for (int j = k >> 1; j > 0; j >>= 1) {
            unsigned long long o = __shfl_xor(v, j);
            const bool asc = ((lane & k) == 0);
            const bool lower = ((lane & j) == 0);
            unsigned long long mn = v < o ? v : o;
            unsigned long long mx = v < o ? o : v;
            v = (lower == asc) ? mn : mx;
        }
    }
}

// merge sorted-asc `best` with sorted-asc `c` (both 64-wide), keep lowest 64 sorted
__device__ __forceinline__ void merge64_u64(unsigned long long& best,
                                            unsigned long long c, int lane) {
    unsigned long long rev = __shfl(c, 63 - lane);
    unsigned long long v = best < rev ? best : rev;
    #pragma unroll
    for (int j = 32; j > 0; j >>= 1) {
        unsigned long long o = __shfl_xor(v, j);
        const bool lower = ((lane & j) == 0);
        unsigned long long mn = v < o ? v : o;
        unsigned long long mx = v < o ? o : v;
        v = lower ? mn : mx;
    }
    best = v;
}

__global__ __launch_bounds__(THREADS, 8)
void lfb_kernel(const float* __restrict__ coords,
                const int* __restrict__ atom_types,
                const float* __restrict__ radii,
                const float* __restrict__ qpts,
                const int* __restrict__ atom_mask,
                const int* __restrict__ query_mask,
                const float* __restrict__ embed,
                const float* __restrict__ centers,
                float* __restrict__ out)
{
    __shared__ __align__(16) float nsx[N_], nsy[N_], nsz[N_];  // NEGATED coords
    __shared__ __align__(16) unsigned char pool[POOLB];        // cand idx / stage

    const int tid  = threadIdx.x;
    const int lane = tid & 63;
    const int wv   = tid >> 6;
    const int bq0  = blockIdx.x * WAVES;
    const int b    = bq0 / Q_;

    // stage negated coords; masked atoms poisoned (-1e30 -> s == +inf bit-exact)
    for (int i = tid; i < N_; i += THREADS) {
        const float* c = coords + (size_t)(b * N_ + i) * 3;
        const bool mv = atom_mask[b * N_ + i] != 0;
        nsx[i] = mv ? -c[0] : -1e30f;
        nsy[i] = mv ? -c[1] : -1e30f;
        nsz[i] = mv ? -c[2] : -1e30f;
    }
    __syncthreads();

    const int bq = bq0 + wv;
    const float qx = qpts[(size_t)bq * 3 + 0];
    const float qy = qpts[(size_t)bq * 3 + 1];
    const float qz = qpts[(size_t)bq * 3 + 2];
    const v2f qx2 = {qx, qx}, qy2 = {qy, qy}, qz2 = {qz, qz};

    const float INFf = __uint_as_float(0x7F800000u);

    // ---- pass 1: full-scan per-lane minima of packed-fma squared dist ----
    float l0 = INFf, l1 = INFf, l2 = INFf, l3 = INFf;
    for (int i = 0; i < N_ / 256; ++i) {
        const int a0 = i * 256 + lane * 4;
        const float4 X = *(const float4*)&nsx[a0];
        const float4 Y = *(const float4*)&nsy[a0];
        const float4 Z = *(const float4*)&nsz[a0];
        const v2f Xl = {X.x, X.y}, Xh = {X.z, X.w};
        const v2f Yl = {Y.x, Y.y}, Yh = {Y.z, Y.w};
        const v2f Zl = {Z.x, Z.y}, Zh = {Z.z, Z.w};
        const v2f sl = pk_s2(qx2, qy2, qz2, Xl, Yl, Zl);
        const v2f sh = pk_s2(qx2, qy2, qz2, Xh, Yh, Zh);
        l0 = fminf(l0, sl.x); l1 = fminf(l1, sl.y);
        l2 = fminf(l2, sh.x); l3 = fminf(l3, sh.y);
    }
    unsigned int mnb = __float_as_uint(fminf(fminf(l0, l1), fminf(l2, l3)));
    bitonic_sort64_u32(mnb, lane);
    const unsigned int Ts = __shfl(mnb, 31);   // 32 witness atoms have s <= Ts
    // +64 bit-steps covers fma-vs-exact divergence through the witness chain
    // AND d-space tie granularity. Guard slop overflow into inf/NaN space.
    const bool degenerate = (Ts + 64u) >= 0x7F800000u;
    const float STf = __uint_as_float(Ts + 64u);

    // ---- pass 2: ballot-collect candidate indices (r4 bookkeeping, u32) ----
    unsigned int* cb = reinterpret_cast<unsigned int*>(pool) + wv * CAP;
    const unsigned long long lt = (1ull << lane) - 1ull;
    int cnt = 0;
    auto collect = [&](float s, int idx) {
        const bool p = s <= STf;               // inf (poisoned) never passes
        const unsigned long long m = __ballot(p);
        if (p) {
            const int sl = cnt + __popcll(m & lt);
            if (sl < CAP) cb[sl] = (unsigned int)idx;
        }
        cnt += __popcll(m);
    };
    for (int i = 0; i < N_ / 256; ++i) {
        const int a0 = i * 256 + lane * 4;
        const float4 X = *(const float4*)&nsx[a0];
        const float4 Y = *(const float4*)&nsy[a0];
        const float4 Z = *(const float4*)&nsz[a0];
        const v2f Xl = {X.x, X.y}, Xh = {X.z, X.w};
        const v2f Yl = {Y.x, Y.y}, Yh = {Y.z, Y.w};
        const v2f Zl = {Z.x, Z.y}, Zh = {Z.z, Z.w};
        const v2f sl = pk_s2(qx2, qy2, qz2, Xl, Yl, Zl);
        const v2f sh = pk_s2(qx2, qy2, qz2, Xh, Yh, Zh);
        collect(sl.x, a0 + 0);
        collect(sl.y, a0 + 1);
        collect(sh.x, a0 + 2);
        collect(sh.y, a0 + 3);
    }

    // exact reference re-key (rn ops, fixed association, eps, CR sqrt)
    auto rekey = [&](int id) -> unsigned long long {
        const float dx = __fadd_rn(qx, nsx[id]);
        const float dy = __fadd_rn(qy, nsy[id]);
        const float dz = __fadd_rn(qz, nsz[id]);
        const float sv = __fadd_rn(
            __fadd_rn(__fmul_rn(dx, dx), __fmul_rn(dy, dy)),
            __fmul_rn(dz, dz));
        const float d = __fsqrt_rn(__fadd_rn(sv, 1e-12f));
        return ((unsigned long long)__float_as_uint(d) << 32) | (unsigned int)id;
    };

    unsigned long long key;
    if (!degenerate && cnt <= CAP) {
        // ---- pass 3: exact (d_bits, idx) sort of the small candidate set ----
        unsigned long long best = ~0ull;
        const int nch = (cnt + 63) >> 6;
        for (int c = 0; c < nch; ++c) {
            const int slot = c * 64 + lane;
            unsigned long long v = ~0ull;
            if (slot < cnt) v = rekey((int)cb[slot]);
            bitonic_sort64_u64(v, lane);
            if (c == 0) best = v;
            else        merge64_u64(best, v, lane);
        }
        key = best;
    } else {
        // fallback (degenerate masks / flooded threshold): exact streaming scan
        key = ~0ull;
        for (int base = 0; base < N_; base += 64) {
            const unsigned long long cand = rekey(base + lane);
            const unsigned long long T = __shfl(key, 31);
            unsigned long long m = __ballot(cand < T);
            while (m) {
                const int src = __ffsll(m) - 1;
                m &= m - 1;
                const unsigned long long nk = __shfl(cand, src);
                const unsigned long long up = __shfl_up(key, 1);
                if (lane < K_) {
                    const unsigned long long repl =
                        (lane == 0) ? nk : (up <= nk ? nk : up);
                    key = (key <= nk) ? key : repl;
                }
            }
        }
    }

    const size_t BQK = (size_t)B_ * Q_ * K_;
    float* out_feat = out;
    float* out_mask = out + BQK * (size_t)F_;
    float* out_idx  = out_mask + BQK;
    float* out_dist = out_idx + BQK;

    const bool qm = query_mask[bq] != 0;

    const float d_l  = __uint_as_float((unsigned int)(key >> 32));
    const int   id_l = (int)(key & 0xFFFFFFFFull) & (N_ - 1);
    const bool  am_l = ((unsigned int)(key >> 32)) < 0x7F800000u;  // d < inf
    const bool  nm_l = am_l && (d_l <= 5.0f) && qm;

    // scalar outputs before the stage-overlay barrier
    if (lane < K_) {
        const size_t o = (size_t)bq * K_ + lane;
        out_mask[o] = nm_l ? 1.0f : 0.0f;
        out_idx[o]  = am_l ? (float)id_l : -1.0f;
        out_dist[o] = nm_l ? d_l : 0.0f;
    }

    __syncthreads();   // all cand-buffer reads done before stage overlay

    // ---- feature build: NSLOT stage slots, 4 barrier rounds ----
    float* stagef = reinterpret_cast<float*>(pool);
    for (int r = 0; r < WAVES / NSLOT; ++r) {
        if ((wv >> 2) == r) {
            float* f0 = stagef + (size_t)(wv & (NSLOT - 1)) * TILE;
            if (lane < K_) {
                float* f = f0 + lane * F_;
                f[0] = nm_l ? __fadd_rn(qx, nsx[id_l]) : 0.0f;
                f[1] = nm_l ? __fadd_rn(qy, nsy[id_l]) : 0.0f;
                f[2] = nm_l ? __fadd_rn(qz, nsz[id_l]) : 0.0f;
                f[3] = nm_l ? radii[b * N_ + id_l] : 0.0f;

                const int t = atom_types[b * N_ + id_l];
                const float4* er4 = (const float4*)(embed + t * E_);
                #pragma unroll
                for (int e = 0; e < E_ / 4; ++e) {
                    const float4 v = er4[e];
                    f[4 + e * 4 + 0] = nm_l ? v.x : 0.0f;
                    f[4 + e * 4 + 1] = nm_l ? v.y : 0.0f;
                    f[4 + e * 4 + 2] = nm_l ? v.z : 0.0f;
                    f[4 + e * 4 + 3] = nm_l ? v.w : 0.0f;
                }

                const float NG = -(float)(256.0 / 25.0);   // -RBF_GAMMA
                #pragma unroll
                for (int rr = 0; rr < R_; ++rr) {
                    const float dd = __fsub_rn(d_l, centers[rr]);
                    const float a2 = __fmul_rn(dd, dd);
                    f[36 + rr] = nm_l ? expf(__fmul_rn(NG, a2)) : 0.0f;
                }
                f[52] = nm_l ? d_l : 0.0f;
            }
            // same-wave LDS in-order: copy sees this wave's writes w/o barrier
            const float4* s4 = (const float4*)f0;
            float4* d4 = (float4*)(out_feat + (size_t)bq * (size_t)TILE);
            for (int t4 = lane; t4 < TILE / 4; t4 += 64) d4[t4] = s4[t4];
        }
        __syncthreads();
    }
}

extern "C" void kernel_launch(void* const* d_in, const int* in_sizes, int n_in,
                              void* d_out, int out_size, void* d_ws, size_t ws_size,
                              hipStream_t stream) {
    const float* coords     = (const float*)d_in[0];
    const int*   atom_types = (const int*)d_in[1];
    const float* radii      = (const float*)d_in[2];
    const float* qpts       = (const float*)d_in[3];
    const int*   atom_mask  = (const int*)d_in[4];
    const int*   query_mask = (const int*)d_in[5];
    const float* embed      = (const float*)d_in[6];
    const float* centers    = (const float*)d_in[7];

    dim3 grid((B_ * Q_) / WAVES);
    dim3 block(THREADS);
    lfb_kernel<<<grid, block, 0, stream>>>(coords, atom_types, radii, qpts,
                                           atom_mask, query_mask, embed, centers,
                                           (float*)d_out);
}